// Round 7
// baseline (366.442 us; speedup 1.0000x reference)
//
#include <hip/hip_runtime.h>
#include <hip/hip_bf16.h>

#define NN 20000
#define NE 320000
#define NG 256
#define DD 256
#define NL 4
#define NBKT 79    // ceil(NN/256) scan buckets
#define BM 80      // gemm rows per block: 250*80 == 20000 exactly
#define NBLK 250   // NN/BM

typedef __attribute__((ext_vector_type(8))) short short8;
typedef __attribute__((ext_vector_type(4))) float float4_t;

// flags[0]=1 if edge_index int64; flags[1]=1 if batch int64; flags[2]=1 if floats bf16
__device__ __forceinline__ int ld_idx(const int* __restrict__ p, int i, int f64) {
    return f64 ? p[2 * i] : p[i];
}

__device__ __forceinline__ float bf2f(ushort u) {
    return __uint_as_float(((unsigned)u) << 16);
}

__device__ __forceinline__ ushort f2bf(float f) {
    __hip_bfloat16 b = __float2bfloat16(f);
    return *(ushort*)&b;
}

// ---------------- init: zero deg, dtype detection (block 0) ----

__global__ void k_init(const int* __restrict__ ei, const int* __restrict__ batch,
                       const ushort* __restrict__ x, int* __restrict__ flags,
                       int* __restrict__ deg) {
    int gid = blockIdx.x * 256 + threadIdx.x;
    for (int i = gid; i < NN; i += gridDim.x * 256) deg[i] = 0;
    if (blockIdx.x == 0) {
        __shared__ int cnt0, cnt1, weird;
        int t = threadIdx.x;
        if (t == 0) { cnt0 = 0; cnt1 = 0; weird = 0; }
        __syncthreads();
        for (int tt = t; tt < 512; tt += 256) {
            if (ei[2 * tt + 1] != 0) atomicAdd(&cnt0, 1);
            int i = tt * 9;
            if (batch[2 * i + 1] != 0) atomicAdd(&cnt1, 1);
#pragma unroll
            for (int j = 0; j < 16; j++) {
                ushort v = x[tt * 16 + j];
                if (((v >> 7) & 0xFF) >= 0xC0) atomicAdd(&weird, 1);
            }
        }
        __syncthreads();
        if (t == 0) {
            flags[0] = (cnt0 == 0) ? 1 : 0;
            flags[1] = (cnt1 == 0) ? 1 : 0;
            flags[2] = (weird == 0) ? 1 : 0;
        }
    }
}

// ---------------- fused prep: cvt8 | WtF frag-build(tiled) | cvtp | degree | gstart

#define POFF_BL   0
#define POFF_GA   1024
#define POFF_BE   2048
#define POFF_F1W  3072
#define POFF_F1B  35840
#define POFF_F2W  35968
#define POFF_F2B  44160
#define POFF_F3W  44224
#define POFF_F3B  44864
#define PTOT      44874

#define NB_CVT8   2500            // NN*DD/8/256
#define NB_FRAG   128             // 8 matrices x 16 (64x64) tiles
#define NB_CVTP   176             // ceil(PTOT/256)
#define NB_DEG    1250            // NE/256
#define NB_GST    79              // ceil(NN/256)
#define B_FRAG    (NB_CVT8)
#define B_CVTP    (B_FRAG + NB_FRAG)
#define B_DEG     (B_CVTP + NB_CVTP)
#define B_GST     (B_DEG + NB_DEG)
#define NB_PREP   (B_GST + NB_GST)

// WtF fragment layout (per 256x256 matrix, 65536 elems):
//   element (n,k) lives at  ((n>>4)*8 + (k>>5))*512 + ((n&15) + 16*((k>>3)&3))*8 + (k&7)
// so a wave's B-fragment load is base + lane*8 (lane-contiguous 16B -> coalesced).

__global__ __launch_bounds__(256) void k_prep(
    const void* __restrict__ x_in, const void* __restrict__ WL,
    const void* __restrict__ WR, const int* __restrict__ ei,
    const int* __restrict__ batch,
    const void* s0, const void* s1, const void* s2, const void* s3,
    const void* s4, const void* s5, const void* s6, const void* s7, const void* s8,
    ushort* __restrict__ xcan, ushort* __restrict__ wtL, ushort* __restrict__ wtR,
    ushort* __restrict__ pcan, int* __restrict__ deg, int* __restrict__ gstart,
    const int* __restrict__ fl) {
    int blk = blockIdx.x;
    int t = threadIdx.x;
    if (blk < B_FRAG) {
        // x canonicalization, 8 elems/lane
        int i = blk * 256 + t;
        if (fl[2]) {
            *(int4*)(xcan + (size_t)i * 8) = ((const int4*)x_in)[i];
        } else {
            const float* f = (const float*)x_in + (size_t)i * 8;
            ushort ov[8];
#pragma unroll
            for (int d = 0; d < 8; d++) ov[d] = f2bf(f[d]);
            *(int4*)(xcan + (size_t)i * 8) = *(int4*)ov;
        }
    } else if (blk < B_CVTP) {
        // tiled B-fragment build: LDS transpose, coalesced in and out
        __shared__ ushort T[64][65];   // T[n_local][k_local]
        int bid = blk - B_FRAG;        // 0..127
        int lm = bid >> 4;             // 0..7 (0-3: L, 4-7: R)
        int tile = bid & 15;
        int tk = (tile >> 2) * 64, tn = (tile & 3) * 64;
        const void* W = (lm >= 4) ? WR : WL;
        ushort* Wt = (lm >= 4) ? wtR : wtL;
        size_t base = (size_t)(lm & 3) << 16;
        int f32 = !fl[2];
#pragma unroll
        for (int i = 0; i < 16; i++) {
            int flat = t + i * 256;
            int r = flat >> 6, c = flat & 63;   // read W[tk+r][tn+c], coalesced in c
            size_t src = base + (size_t)(tk + r) * 256 + tn + c;
            ushort v = f32 ? f2bf(((const float*)W)[src]) : ((const ushort*)W)[src];
            T[c][r] = v;
        }
        __syncthreads();
        // write 16B/thread in fragment order (coalesced)
#pragma unroll
        for (int i = 0; i < 2; i++) {
            int slot = t + i * 256;            // 0..511
            int f = slot >> 6;                 // local fblk 0..7
            int lane = slot & 63;
            int ln = (f >> 1) * 16 + (lane & 15);
            int lk = (f & 1) * 32 + ((lane >> 4) << 3);
            int gfblk = ((tn + ln) >> 4) * 8 + ((tk + lk) >> 5);
            ushort tmp[8];
#pragma unroll
            for (int j = 0; j < 8; j++) tmp[j] = T[ln][lk + j];
            *(int4*)(Wt + base + (size_t)gfblk * 512 + lane * 8) = *(int4*)tmp;
        }
    } else if (blk < B_DEG) {
        // small params
        int i = (blk - B_CVTP) * 256 + t;
        if (i >= PTOT) return;
        const int offs[10] = {POFF_BL, POFF_GA, POFF_BE, POFF_F1W, POFF_F1B,
                              POFF_F2W, POFF_F2B, POFF_F3W, POFF_F3B, PTOT};
        const void* srcs[9] = {s0, s1, s2, s3, s4, s5, s6, s7, s8};
        int seg = 0;
#pragma unroll
        for (int k = 1; k < 9; k++) if (i >= offs[k]) seg = k;
        int local = i - offs[seg];
        if (fl[2]) pcan[i] = ((const ushort*)srcs[seg])[local];
        else       pcan[i] = f2bf(((const float*)srcs[seg])[local]);
    } else if (blk < B_GST) {
        // degree
        int e = (blk - B_DEG) * 256 + t;
        if (e < NE) {
            int src = ld_idx(ei, e, fl[0]);
            int dst = ld_idx(ei, NE + e, fl[0]);
            if ((unsigned)dst < NN && (unsigned)src < NN) atomicAdd(&deg[dst], 1);
        }
    } else {
        // gstart
        int i = (blk - B_GST) * 256 + t;
        if (i >= NN) return;
        int b = ld_idx(batch, i, fl[1]);
        int bp = (i == 0) ? -1 : ld_idx(batch, i - 1, fl[1]);
        for (int g = bp + 1; g <= b; g++)
            if ((unsigned)g <= NG) gstart[g] = i;
        if (i == NN - 1)
            for (int g = b + 1; g <= NG; g++) gstart[g] = NN;
    }
}

// -------- merged scan: each block redundantly reduces its prefix (cheap: <=80KB)

__global__ __launch_bounds__(256) void k_scan(
    const int* __restrict__ deg, int* __restrict__ rowst,
    int* __restrict__ cursor, float* __restrict__ invdeg) {
    __shared__ int red[256];
    __shared__ int part[256];
    int b = blockIdx.x, t = threadIdx.x;
    // bpref = sum(deg[0 .. 256*b))
    int s = 0;
    for (int i = t; i < b * 256; i += 256) s += deg[i];
    red[t] = s;
    __syncthreads();
    for (int off = 128; off; off >>= 1) {
        if (t < off) red[t] += red[t + off];
        __syncthreads();
    }
    int bpref = red[0];
    int node = b * 256 + t;
    int d = (node < NN) ? deg[node] : 0;
    part[t] = d;
    __syncthreads();
    for (int off = 1; off < 256; off <<= 1) {
        int v = (t >= off) ? part[t - off] : 0;
        __syncthreads();
        part[t] += v;
        __syncthreads();
    }
    if (node < NN) {
        int o = bpref + part[t] - d;
        rowst[node] = o;
        cursor[node] = o;
        invdeg[node] = d > 0 ? 1.0f / (float)d : 0.0f;
    }
    if (b == NBKT - 1 && t == 255) rowst[NN] = bpref + part[255];
}

__global__ void k_fill(const int* __restrict__ ei, int* __restrict__ cursor,
                       int* __restrict__ csr, const int* __restrict__ fl) {
    int e = blockIdx.x * 256 + threadIdx.x;
    if (e < NE) {
        int src = ld_idx(ei, e, fl[0]);
        int dst = ld_idx(ei, NE + e, fl[0]);
        if ((unsigned)dst < NN && (unsigned)src < NN) {
            int p = atomicAdd(&cursor[dst], 1);
            if ((unsigned)p < NE) csr[p] = src;
        }
    }
}

// ------- dim-sliced mean aggregation (clean L2-residency test) ---------------
// 4 slices x 64 dims: per-slice X working set = 20000*128B = 2.56MB < 4MB XCD
// L2. s = blockIdx&3: under default round-robin block->XCD dispatch, XCD k
// caches exactly slice k&3. Wave = 4 nodes x (8 dim-lanes x 2 edge-parity);
// per-(node,dim) loops are verbatim k_agg4 (same 8-batch/pair/tail, same
// h0+h1 combine) -> bit-identical AGG. Masked lanes fetch nothing, so degree
// divergence (max-of-4) wastes issue slots only, not bytes.

template <int BNF>
__global__ __launch_bounds__(256) void k_agg6(
    const ushort* __restrict__ X, const int* __restrict__ rs,
    const int* __restrict__ csr, const float* __restrict__ invdeg,
    const float* __restrict__ bnsc, const float* __restrict__ bnsh,
    ushort* __restrict__ AGG) {
    const int s = blockIdx.x & 3;            // dim slice 0..3
    const int chunk = blockIdx.x >> 2;       // 0..1249
    const int tid = threadIdx.x;
    const int w = tid >> 6, lane = tid & 63;
    const int nw = lane >> 4;                // node within wave 0..3
    const int h = (lane >> 3) & 1;           // edge parity
    const int jl = lane & 7;                 // dim-lane 0..7
    const int db = s * 64 + jl * 8;          // 8 dims per lane
    const int node = chunk * 16 + w * 4 + nw;   // exact: 1250*16 = 20000
    float sc[8], sh[8];
    if (BNF) {
        float4 a0 = *(const float4*)(bnsc + db);
        float4 a1 = *(const float4*)(bnsc + db + 4);
        float4 b0 = *(const float4*)(bnsh + db);
        float4 b1 = *(const float4*)(bnsh + db + 4);
        sc[0] = a0.x; sc[1] = a0.y; sc[2] = a0.z; sc[3] = a0.w;
        sc[4] = a1.x; sc[5] = a1.y; sc[6] = a1.z; sc[7] = a1.w;
        sh[0] = b0.x; sh[1] = b0.y; sh[2] = b0.z; sh[3] = b0.w;
        sh[4] = b1.x; sh[5] = b1.y; sh[6] = b1.z; sh[7] = b1.w;
    }
    int e0 = rs[node], e1 = rs[node + 1];
    float acc[8] = {};
    int e = e0 + h;
    for (; e + 14 < e1; e += 16) {     // 8 independent row-slice loads in flight
        int4 v[8];
#pragma unroll
        for (int r = 0; r < 8; r++) {
            int src = csr[e + 2 * r];
            v[r] = *(const int4*)(X + (size_t)src * DD + db);
        }
#pragma unroll
        for (int r = 0; r < 8; r++) {
            const ushort* u = (const ushort*)&v[r];
#pragma unroll
            for (int d = 0; d < 8; d++) {
                float x = bf2f(u[d]);
                if (BNF) x = fmaxf(x * sc[d] + sh[d], 0.0f);
                acc[d] += x;
            }
        }
    }
    for (; e + 2 < e1; e += 4) {       // pairs
        int sA = csr[e], sB = csr[e + 2];
        int4 vA = *(const int4*)(X + (size_t)sA * DD + db);
        int4 vB = *(const int4*)(X + (size_t)sB * DD + db);
        const ushort* uA = (const ushort*)&vA;
        const ushort* uB = (const ushort*)&vB;
#pragma unroll
        for (int d = 0; d < 8; d++) {
            float xA = bf2f(uA[d]), xB = bf2f(uB[d]);
            if (BNF) {
                xA = fmaxf(xA * sc[d] + sh[d], 0.0f);
                xB = fmaxf(xB * sc[d] + sh[d], 0.0f);
            }
            acc[d] += xA + xB;
        }
    }
    for (; e < e1; e += 2) {
        int src = csr[e];
        int4 v = *(const int4*)(X + (size_t)src * DD + db);
        const ushort* u = (const ushort*)&v;
#pragma unroll
        for (int d = 0; d < 8; d++) {
            float x = bf2f(u[d]);
            if (BNF) x = fmaxf(x * sc[d] + sh[d], 0.0f);
            acc[d] += x;
        }
    }
#pragma unroll
    for (int d = 0; d < 8; d++)
        acc[d] += __shfl_down(acc[d], 8);   // h0 + h1, same operand order as agg4
    if (h == 0) {
        float inv = invdeg[node];
        ushort ov[8];
#pragma unroll
        for (int d = 0; d < 8; d++) ov[d] = f2bf(acc[d] * inv);
        *(int4*)(AGG + (size_t)node * DD + db) = *(int4*)ov;
    }
}

// ------- 80x128 GEMM, B-panel in registers -----------------------------------
// Per wave the whole B strip (32 cols x 256 K) is 16 fragments = 64 VGPRs.
// Preloaded per mat before the A staging barrier: L2 latency paid once, hidden
// under staging; the K loop touches only LDS (A) + registers (B). MFMA order,
// staging, epilogue identical to gemm6 -> bit-identical output.

template <int BNF>
__global__ __launch_bounds__(256, 3) void k_gemm8(
    const ushort* __restrict__ A1, const ushort* __restrict__ A2,
    const ushort* __restrict__ WtF1, const ushort* __restrict__ WtF2,
    const ushort* __restrict__ bias,
    const float* __restrict__ bnsc, const float* __restrict__ bnsh,
    ushort* __restrict__ H, float* __restrict__ psumT, float* __restrict__ psqT) {
    __shared__ ushort Als[BM][264];       // 80x264x2 = 42.2KB, stride 528B (2-way ok)
    __shared__ float colsum[128];
    __shared__ float colsq[128];
    const int m0 = blockIdx.x * BM;
    const int n0 = blockIdx.y * 128;
    const int tid = threadIdx.x;
    const int w = tid >> 6, lane = tid & 63;
    const int lr = lane & 15, q = lane >> 4;
    float4_t acc[5][2] = {};

    if (tid < 128) { colsum[tid] = 0.0f; colsq[tid] = 0.0f; }

    for (int mat = 0; mat < 2; ++mat) {
        const ushort* A = mat ? A2 : A1;
        const ushort* Wf = mat ? WtF2 : WtF1;
        // preload this wave's 16 B fragments (independent L2 loads, deep ILP)
        short8 bfr[8][2];
        const ushort* bb0 =
            Wf + (((size_t)(((n0 + w * 32) >> 4) * 8)) << 9) + lane * 8;
#pragma unroll
        for (int k8 = 0; k8 < 8; k8++)
#pragma unroll
            for (int in = 0; in < 2; in++)
                bfr[k8][in] = *(const short8*)(bb0 + (size_t)k8 * 512 + in * 4096);
        __syncthreads();                   // Als reads of prev mat done (also covers colsum init)
        // stage 80 rows x 256 cols: 2560 int4, 10 per thread, row-contiguous
#pragma unroll
        for (int i = 0; i < 10; i++) {
            int flat = tid + i * 256;      // 0..2559
            int r = flat >> 5;             // 0..79
            int c = (flat & 31) * 8;       // elem col 0..248
            int4 av = *(const int4*)(A + (size_t)(m0 + r) * DD + c);
            if (BNF && mat == 1) {
                ushort* u = (ushort*)&av;
#pragma unroll
                for (int d = 0; d < 8; d++)
                    u[d] = f2bf(fmaxf(bf2f(u[d]) * bnsc[c + d] + bnsh[c + d], 0.0f));
            }
            *(int4*)&Als[r][c] = av;
        }
        __syncthreads();
        // K loop: wave w covers cols n0 + w*32 .. +31, all 80 rows; B from regs
#pragma unroll
        for (int k0 = 0; k0 < 256; k0 += 32) {
            short8 af[5];
#pragma unroll
            for (int im = 0; im < 5; im++)
                af[im] = *(const short8*)&Als[im * 16 + lr][k0 + q * 8];
#pragma unroll
            for (int in = 0; in < 2; in++) {
#pragma unroll
                for (int im = 0; im < 5; im++)
                    acc[im][in] = __builtin_amdgcn_mfma_f32_16x16x32_bf16(
                        af[im], bfr[k0 >> 5][in], acc[im][in], 0, 0, 0);
            }
        }
    }

    // epilogue: C/D layout col=lane&15, row=(lane>>4)*4+reg
    const int mbase = m0 + q * 4;
#pragma unroll
    for (int in = 0; in < 2; ++in) {
        const int nl = w * 32 + in * 16 + lr;   // 0..127 local col
        const int n = n0 + nl;
        float b = bf2f(bias[n]);
        float s = 0.0f, s2 = 0.0f;
#pragma unroll
        for (int im = 0; im < 5; ++im) {
#pragma unroll
            for (int i = 0; i < 4; ++i) {
                int m = mbase + im * 16 + i;     // always < NN (exact tiling)
                float hv = acc[im][in][i] + b;
                ushort hb = f2bf(hv);
                H[(size_t)m * DD + n] = hb;
                float hq = bf2f(hb);
                s += hq;
                s2 += hq * hq;
            }
        }
        s += __shfl_xor(s, 16);  s += __shfl_xor(s, 32);
        s2 += __shfl_xor(s2, 16); s2 += __shfl_xor(s2, 32);
        if (q == 0) {
            atomicAdd(&colsum[nl], s);
            atomicAdd(&colsq[nl], s2);
        }
    }
    __syncthreads();
    if (tid < 128) {
        psumT[(size_t)(n0 + tid) * 256 + blockIdx.x] = colsum[tid];
        psqT[(size_t)(n0 + tid) * 256 + blockIdx.x] = colsq[tid];
    }
}

// ---------------- BN finalize (separate dispatch; kernel boundary = release) --
// Reads transposed psumT coalesced; partial order (b = t + 64k ascending) and
// shfl_down tree identical to the original -> bit-identical scale/shift.

__global__ __launch_bounds__(64) void k_bnfinal3(
    const float* __restrict__ psumT, const float* __restrict__ psqT,
    const ushort* __restrict__ gamma, const ushort* __restrict__ beta,
    float* __restrict__ scale, float* __restrict__ shift) {
    int c = blockIdx.x;     // 256
    int t = threadIdx.x;    // 64
    float s = 0.0f, s2 = 0.0f;
    for (int b = t; b < NBLK; b += 64) {
        s += psumT[(size_t)c * 256 + b];
        s2 += psqT[(size_t)c * 256 + b];
    }
#pragma unroll
    for (int o = 32; o; o >>= 1) {
        s += __shfl_down(s, o);
        s2 += __shfl_down(s2, o);
    }
    if (t == 0) {
        float mu = s * (1.0f / NN);
        float var = s2 * (1.0f / NN) - mu * mu;
        if (var < 0.0f) var = 0.0f;
        float rstd = rsqrtf(var + 1e-5f);
        float g = bf2f(gamma[c]);
        float b2 = bf2f(beta[c]);
        scale[c] = g * rstd;
        shift[c] = b2 - mu * g * rstd;
    }
}

// ---------------- fused pool (lazy BN) + MLP, weights in LDS ----------------
// Pool keeps per-dim ascending-i accumulation order (bit-identical); only the
// loads are batched 8-wide for latency hiding. MLP k-loops unchanged in order.

__global__ __launch_bounds__(256) void k_head(
    const ushort* __restrict__ Hb, const float* __restrict__ scale,
    const float* __restrict__ shift, const int* __restrict__ gstart,
    const ushort* __restrict__ fc1w, const ushort* __restrict__ fc1b,
    const ushort* __restrict__ fc2w, const ushort* __restrict__ fc2b,
    const ushort* __restrict__ fc3w, const ushort* __restrict__ fc3b,
    void* __restrict__ out, const int* __restrict__ fl) {
    __shared__ float g[256];
    __shared__ float h1[128];
    __shared__ float h2[64];
    __shared__ ushort w1[256 * 128];   // 64 KB
    __shared__ ushort w2[128 * 64];    // 16 KB
    __shared__ ushort w3[64 * 10];     // 1.25 KB
    int gid = blockIdx.x;
    int t = threadIdx.x;
    // stage MLP weights coalesced (int4 = 8 ushorts)
    for (int i = t; i < 256 * 128 / 8; i += 256) ((int4*)w1)[i] = ((const int4*)fc1w)[i];
    for (int i = t; i < 128 * 64 / 8; i += 256) ((int4*)w2)[i] = ((const int4*)fc2w)[i];
    if (t < 80) ((int4*)w3)[t] = ((const int4*)fc3w)[t];

    int s0 = gstart[gid], e = gstart[gid + 1];
    float sc = scale[t], sh = shift[t];
    float acc = 0.0f;
    int i = s0;
    for (; i + 7 < e; i += 8) {        // 8 loads in flight, adds stay in order
        float v[8];
#pragma unroll
        for (int r = 0; r < 8; r++) v[r] = bf2f(Hb[(size_t)(i + r) * DD + t]);
#pragma unroll
        for (int r = 0; r < 8; r++) acc += fmaxf(v[r] * sc + sh, 0.0f);
    }
    for (; i < e; i++)
        acc += fmaxf(bf2f(Hb[(size_t)i * DD + t]) * sc + sh, 0.0f);
    g[t] = acc / fmaxf((float)(e - s0), 1.0f);
    __syncthreads();
    if (t < 128) {
        float a = bf2f(fc1b[t]);
#pragma unroll 8
        for (int k = 0; k < 256; k++)
            a += g[k] * bf2f(w1[k * 128 + t]);
        h1[t] = fmaxf(a, 0.0f);
    }
    __syncthreads();
    if (t < 64) {
        float a2 = bf2f(fc2b[t]);
#pragma unroll 8
        for (int k = 0; k < 128; k++)
            a2 += h1[k] * bf2f(w2[k * 64 + t]);
        h2[t] = fmaxf(a2, 0.0f);
    }
    __syncthreads();
    if (t < 10) {
        float a3 = bf2f(fc3b[t]);
#pragma unroll 8
        for (int k = 0; k < 64; k++)
            a3 += h2[k] * bf2f(w3[k * 10 + t]);
        if (fl[2]) ((__hip_bfloat16*)out)[gid * 10 + t] = __float2bfloat16(a3);
        else       ((float*)out)[gid * 10 + t] = a3;
    }
}

// ---------------- host ----------------

static inline char* bump(char*& p, size_t n) {
    char* r = p;
    p += (n + 255) & ~(size_t)255;
    return r;
}

extern "C" void kernel_launch(void* const* d_in, const int* in_sizes, int n_in,
                              void* d_out, int out_size, void* d_ws, size_t ws_size,
                              hipStream_t stream) {
    const void* x_in  = d_in[0];
    const int*  ei    = (const int*)d_in[1];
    const int*  batch = (const int*)d_in[2];
    const void* Wl    = d_in[3];
    const void* bl    = d_in[4];
    const void* Wr    = d_in[5];
    const void* gamma = d_in[6];
    const void* beta  = d_in[7];

    char* p = (char*)d_ws;
    int*    flags    = (int*)bump(p, 256);
    ushort* wtL      = (ushort*)bump(p, (size_t)NL * 65536 * 2);   // fragment layout
    ushort* wtR      = (ushort*)bump(p, (size_t)NL * 65536 * 2);   // fragment layout
    ushort* xcan     = (ushort*)bump(p, (size_t)NN * DD * 2);
    ushort* pcan     = (ushort*)bump(p, (size_t)PTOT * 2);
    int*    deg      = (int*)bump(p, NN * 4);
    int*    rowst    = (int*)bump(p, (NN + 1) * 4);
    int*    cursor   = (int*)bump(p, NN * 4);
    float*  invdeg   = (float*)bump(p, NN * 4);
    int*    csr      = (int*)bump(p, NE * 4);
    int*    gstart   = (int*)bump(p, (NG + 1) * 4);
    ushort* agg      = (ushort*)bump(p, (size_t)NN * DD * 2);
    ushort* hb0      = (ushort*)bump(p, (size_t)NN * DD * 2);
    ushort* hb1      = (ushort*)bump(p, (size_t)NN * DD * 2);
    float*  psumT    = (float*)bump(p, (size_t)DD * 256 * 4);
    float*  psqT     = (float*)bump(p, (size_t)DD * 256 * 4);
    float*  scale    = (float*)bump(p, DD * 4);
    float*  shift    = (float*)bump(p, DD * 4);

    if ((size_t)(p - (char*)d_ws) > ws_size) return;

    ushort* blc = pcan + POFF_BL;
    ushort* gac = pcan + POFF_GA;
    ushort* bec = pcan + POFF_BE;
    ushort* f1w = pcan + POFF_F1W;
    ushort* f1b = pcan + POFF_F1B;
    ushort* f2w = pcan + POFF_F2W;
    ushort* f2b = pcan + POFF_F2B;
    ushort* f3w = pcan + POFF_F3W;
    ushort* f3b = pcan + POFF_F3B;

    k_init<<<80, 256, 0, stream>>>(ei, batch, (const ushort*)x_in, flags, deg);
    k_prep<<<NB_PREP, 256, 0, stream>>>(
        x_in, Wl, Wr, ei, batch,
        bl, gamma, beta, d_in[8], d_in[9], d_in[10], d_in[11], d_in[12], d_in[13],
        xcan, wtL, wtR, pcan, deg, gstart, flags);
    k_scan<<<NBKT, 256, 0, stream>>>(deg, rowst, cursor, invdeg);
    k_fill<<<(NE + 255) / 256, 256, 0, stream>>>(ei, cursor, csr, flags);

    ushort* hbuf[2] = {hb0, hb1};
    const ushort* xsrc = xcan;
    for (int l = 0; l < NL; l++) {
        ushort* hdst = hbuf[l & 1];
        const ushort* wl = wtL + (size_t)l * 65536;
        const ushort* wr = wtR + (size_t)l * 65536;
        if (l == 0) {
            k_agg6<0><<<5000, 256, 0, stream>>>(xsrc, rowst, csr, invdeg,
                                                scale, shift, agg);
            k_gemm8<0><<<dim3(NBLK, 2), 256, 0, stream>>>(
                agg, xsrc, wl, wr, blc, scale, shift, hdst, psumT, psqT);
        } else {
            k_agg6<1><<<5000, 256, 0, stream>>>(xsrc, rowst, csr, invdeg,
                                                scale, shift, agg);
            k_gemm8<1><<<dim3(NBLK, 2), 256, 0, stream>>>(
                agg, xsrc, wl, wr, blc + l * DD, scale, shift, hdst, psumT, psqT);
        }
        k_bnfinal3<<<DD, 64, 0, stream>>>(psumT, psqT, gac + l * DD, bec + l * DD,
                                          scale, shift);
        xsrc = hdst;
    }

    k_head<<<NG, 256, 0, stream>>>(xsrc, scale, shift, gstart,
                                   f1w, f1b, f2w, f2b, f3w, f3b, d_out, flags);
}

// Round 8
// 346.029 us; speedup vs baseline: 1.0590x; 1.0590x over previous
//
#include <hip/hip_runtime.h>
#include <hip/hip_bf16.h>

#define NN 20000
#define NE 320000
#define NG 256
#define DD 256
#define NL 4
#define NBKT 79    // ceil(NN/256) scan buckets
#define BM 80      // gemm rows per block: 250*80 == 20000 exactly
#define NBLK 250   // NN/BM

typedef __attribute__((ext_vector_type(8))) short short8;
typedef __attribute__((ext_vector_type(4))) float float4_t;

// flags[0]=1 if edge_index int64; flags[1]=1 if batch int64; flags[2]=1 if floats bf16
__device__ __forceinline__ int ld_idx(const int* __restrict__ p, int i, int f64) {
    return f64 ? p[2 * i] : p[i];
}

__device__ __forceinline__ float bf2f(ushort u) {
    return __uint_as_float(((unsigned)u) << 16);
}

__device__ __forceinline__ ushort f2bf(float f) {
    __hip_bfloat16 b = __float2bfloat16(f);
    return *(ushort*)&b;
}

// ---------------- init (fallback): zero deg, dtype detection (block 0) ----

__global__ void k_init(const int* __restrict__ ei, const int* __restrict__ batch,
                       const ushort* __restrict__ x, int* __restrict__ flags,
                       int* __restrict__ deg) {
    int gid = blockIdx.x * 256 + threadIdx.x;
    for (int i = gid; i < NN; i += gridDim.x * 256) deg[i] = 0;
    if (blockIdx.x == 0) {
        __shared__ int cnt0, cnt1, weird;
        int t = threadIdx.x;
        if (t == 0) { cnt0 = 0; cnt1 = 0; weird = 0; }
        __syncthreads();
        for (int tt = t; tt < 512; tt += 256) {
            if (ei[2 * tt + 1] != 0) atomicAdd(&cnt0, 1);
            int i = tt * 9;
            if (batch[2 * i + 1] != 0) atomicAdd(&cnt1, 1);
#pragma unroll
            for (int j = 0; j < 16; j++) {
                ushort v = x[tt * 16 + j];
                if (((v >> 7) & 0xFF) >= 0xC0) atomicAdd(&weird, 1);
            }
        }
        __syncthreads();
        if (t == 0) {
            flags[0] = (cnt0 == 0) ? 1 : 0;
            flags[1] = (cnt1 == 0) ? 1 : 0;
            flags[2] = (weird == 0) ? 1 : 0;
        }
    }
}

// ---------------- init (fast path): dtypes known host-side from in_sizes ----

__global__ void k_init2(int* __restrict__ flags, int* __restrict__ deg,
                        int f0, int f1, int f2) {
    int gid = blockIdx.x * 256 + threadIdx.x;
    for (int i = gid; i < NN; i += gridDim.x * 256) deg[i] = 0;
    if (gid == 0) { flags[0] = f0; flags[1] = f1; flags[2] = f2; }
}

// ---------------- fused prep: cvt8 | WtF frag-build(tiled) | cvtp | degree | gstart
// blkoff shifts block decoding so the cvt8 range can be skipped when the input
// is already bf16 (host-known): launch NB_PREP-NB_CVT8 blocks with blkoff=NB_CVT8.

#define POFF_BL   0
#define POFF_GA   1024
#define POFF_BE   2048
#define POFF_F1W  3072
#define POFF_F1B  35840
#define POFF_F2W  35968
#define POFF_F2B  44160
#define POFF_F3W  44224
#define POFF_F3B  44864
#define PTOT      44874

#define NB_CVT8   2500            // NN*DD/8/256
#define NB_FRAG   128             // 8 matrices x 16 (64x64) tiles
#define NB_CVTP   176             // ceil(PTOT/256)
#define NB_DEG    1250            // NE/256
#define NB_GST    79              // ceil(NN/256)
#define B_FRAG    (NB_CVT8)
#define B_CVTP    (B_FRAG + NB_FRAG)
#define B_DEG     (B_CVTP + NB_CVTP)
#define B_GST     (B_DEG + NB_DEG)
#define NB_PREP   (B_GST + NB_GST)

// WtF fragment layout (per 256x256 matrix, 65536 elems):
//   element (n,k) lives at  ((n>>4)*8 + (k>>5))*512 + ((n&15) + 16*((k>>3)&3))*8 + (k&7)
// so a wave's B-fragment load is base + lane*8 (lane-contiguous 16B -> coalesced).

__global__ __launch_bounds__(256) void k_prep(
    const void* __restrict__ x_in, const void* __restrict__ WL,
    const void* __restrict__ WR, const int* __restrict__ ei,
    const int* __restrict__ batch,
    const void* s0, const void* s1, const void* s2, const void* s3,
    const void* s4, const void* s5, const void* s6, const void* s7, const void* s8,
    ushort* __restrict__ xcan, ushort* __restrict__ wtL, ushort* __restrict__ wtR,
    ushort* __restrict__ pcan, int* __restrict__ deg, int* __restrict__ gstart,
    const int* __restrict__ fl, int blkoff) {
    int blk = blockIdx.x + blkoff;
    int t = threadIdx.x;
    if (blk < B_FRAG) {
        // x canonicalization, 8 elems/lane
        int i = blk * 256 + t;
        if (fl[2]) {
            *(int4*)(xcan + (size_t)i * 8) = ((const int4*)x_in)[i];
        } else {
            const float* f = (const float*)x_in + (size_t)i * 8;
            ushort ov[8];
#pragma unroll
            for (int d = 0; d < 8; d++) ov[d] = f2bf(f[d]);
            *(int4*)(xcan + (size_t)i * 8) = *(int4*)ov;
        }
    } else if (blk < B_CVTP) {
        // tiled B-fragment build: LDS transpose, coalesced in and out
        __shared__ ushort T[64][65];   // T[n_local][k_local]
        int bid = blk - B_FRAG;        // 0..127
        int lm = bid >> 4;             // 0..7 (0-3: L, 4-7: R)
        int tile = bid & 15;
        int tk = (tile >> 2) * 64, tn = (tile & 3) * 64;
        const void* W = (lm >= 4) ? WR : WL;
        ushort* Wt = (lm >= 4) ? wtR : wtL;
        size_t base = (size_t)(lm & 3) << 16;
        int f32 = !fl[2];
#pragma unroll
        for (int i = 0; i < 16; i++) {
            int flat = t + i * 256;
            int r = flat >> 6, c = flat & 63;   // read W[tk+r][tn+c], coalesced in c
            size_t src = base + (size_t)(tk + r) * 256 + tn + c;
            ushort v = f32 ? f2bf(((const float*)W)[src]) : ((const ushort*)W)[src];
            T[c][r] = v;
        }
        __syncthreads();
        // write 16B/thread in fragment order (coalesced)
#pragma unroll
        for (int i = 0; i < 2; i++) {
            int slot = t + i * 256;            // 0..511
            int f = slot >> 6;                 // local fblk 0..7
            int lane = slot & 63;
            int ln = (f >> 1) * 16 + (lane & 15);
            int lk = (f & 1) * 32 + ((lane >> 4) << 3);
            int gfblk = ((tn + ln) >> 4) * 8 + ((tk + lk) >> 5);
            ushort tmp[8];
#pragma unroll
            for (int j = 0; j < 8; j++) tmp[j] = T[ln][lk + j];
            *(int4*)(Wt + base + (size_t)gfblk * 512 + lane * 8) = *(int4*)tmp;
        }
    } else if (blk < B_DEG) {
        // small params
        int i = (blk - B_CVTP) * 256 + t;
        if (i >= PTOT) return;
        const int offs[10] = {POFF_BL, POFF_GA, POFF_BE, POFF_F1W, POFF_F1B,
                              POFF_F2W, POFF_F2B, POFF_F3W, POFF_F3B, PTOT};
        const void* srcs[9] = {s0, s1, s2, s3, s4, s5, s6, s7, s8};
        int seg = 0;
#pragma unroll
        for (int k = 1; k < 9; k++) if (i >= offs[k]) seg = k;
        int local = i - offs[seg];
        if (fl[2]) pcan[i] = ((const ushort*)srcs[seg])[local];
        else       pcan[i] = f2bf(((const float*)srcs[seg])[local]);
    } else if (blk < B_GST) {
        // degree
        int e = (blk - B_CVTP - NB_CVTP) * 256 + t;
        if (e < NE) {
            int src = ld_idx(ei, e, fl[0]);
            int dst = ld_idx(ei, NE + e, fl[0]);
            if ((unsigned)dst < NN && (unsigned)src < NN) atomicAdd(&deg[dst], 1);
        }
    } else {
        // gstart
        int i = (blk - B_GST) * 256 + t;
        if (i >= NN) return;
        int b = ld_idx(batch, i, fl[1]);
        int bp = (i == 0) ? -1 : ld_idx(batch, i - 1, fl[1]);
        for (int g = bp + 1; g <= b; g++)
            if ((unsigned)g <= NG) gstart[g] = i;
        if (i == NN - 1)
            for (int g = b + 1; g <= NG; g++) gstart[g] = NN;
    }
}

// -------- merged scan: each block redundantly reduces its prefix (cheap: <=80KB)

__global__ __launch_bounds__(256) void k_scan(
    const int* __restrict__ deg, int* __restrict__ rowst,
    int* __restrict__ cursor, float* __restrict__ invdeg) {
    __shared__ int red[256];
    __shared__ int part[256];
    int b = blockIdx.x, t = threadIdx.x;
    // bpref = sum(deg[0 .. 256*b))
    int s = 0;
    for (int i = t; i < b * 256; i += 256) s += deg[i];
    red[t] = s;
    __syncthreads();
    for (int off = 128; off; off >>= 1) {
        if (t < off) red[t] += red[t + off];
        __syncthreads();
    }
    int bpref = red[0];
    int node = b * 256 + t;
    int d = (node < NN) ? deg[node] : 0;
    part[t] = d;
    __syncthreads();
    for (int off = 1; off < 256; off <<= 1) {
        int v = (t >= off) ? part[t - off] : 0;
        __syncthreads();
        part[t] += v;
        __syncthreads();
    }
    if (node < NN) {
        int o = bpref + part[t] - d;
        rowst[node] = o;
        cursor[node] = o;
        invdeg[node] = d > 0 ? 1.0f / (float)d : 0.0f;
    }
    if (b == NBKT - 1 && t == 255) rowst[NN] = bpref + part[255];
}

__global__ void k_fill(const int* __restrict__ ei, int* __restrict__ cursor,
                       int* __restrict__ csr, const int* __restrict__ fl) {
    int e = blockIdx.x * 256 + threadIdx.x;
    if (e < NE) {
        int src = ld_idx(ei, e, fl[0]);
        int dst = ld_idx(ei, NE + e, fl[0]);
        if ((unsigned)dst < NN && (unsigned)src < NN) {
            int p = atomicAdd(&cursor[dst], 1);
            if ((unsigned)p < NE) csr[p] = src;
        }
    }
}

// ------- mean aggregation, ILP-8, optional lazy BN+ReLU on gathered rows -----
// 5000 blocks x 256 threads: deep queue -> full occupancy. Runs at the
// streaming vector-load ceiling (~6.3 TB/s chip): 164MB/layer ~= 26 us floor.

template <int BNF>
__global__ __launch_bounds__(256) void k_agg4(
    const ushort* __restrict__ X, const int* __restrict__ rs,
    const int* __restrict__ csr, const float* __restrict__ invdeg,
    const float* __restrict__ bnsc, const float* __restrict__ bnsh,
    ushort* __restrict__ AGG) {
    int node = blockIdx.x * 4 + (threadIdx.x >> 6);
    if (node >= NN) return;
    int h = (threadIdx.x >> 5) & 1;   // half-wave: edges e0+h, e0+h+2, ...
    int j = threadIdx.x & 31;         // dims j*8..j*8+7
    float sc[8], sh[8];
    if (BNF) {
        float4 a0 = *(const float4*)(bnsc + j * 8);
        float4 a1 = *(const float4*)(bnsc + j * 8 + 4);
        float4 b0 = *(const float4*)(bnsh + j * 8);
        float4 b1 = *(const float4*)(bnsh + j * 8 + 4);
        sc[0] = a0.x; sc[1] = a0.y; sc[2] = a0.z; sc[3] = a0.w;
        sc[4] = a1.x; sc[5] = a1.y; sc[6] = a1.z; sc[7] = a1.w;
        sh[0] = b0.x; sh[1] = b0.y; sh[2] = b0.z; sh[3] = b0.w;
        sh[4] = b1.x; sh[5] = b1.y; sh[6] = b1.z; sh[7] = b1.w;
    }
    int e0 = rs[node], e1 = rs[node + 1];
    float acc[8] = {};
    int e = e0 + h;
    for (; e + 14 < e1; e += 16) {     // 8 independent row loads in flight
        int4 v[8];
#pragma unroll
        for (int r = 0; r < 8; r++) {
            int s = csr[e + 2 * r];
            v[r] = *(const int4*)(X + (size_t)s * DD + j * 8);
        }
#pragma unroll
        for (int r = 0; r < 8; r++) {
            const ushort* u = (const ushort*)&v[r];
#pragma unroll
            for (int d = 0; d < 8; d++) {
                float x = bf2f(u[d]);
                if (BNF) x = fmaxf(x * sc[d] + sh[d], 0.0f);
                acc[d] += x;
            }
        }
    }
    for (; e + 2 < e1; e += 4) {       // pairs
        int sA = csr[e], sB = csr[e + 2];
        int4 vA = *(const int4*)(X + (size_t)sA * DD + j * 8);
        int4 vB = *(const int4*)(X + (size_t)sB * DD + j * 8);
        const ushort* uA = (const ushort*)&vA;
        const ushort* uB = (const ushort*)&vB;
#pragma unroll
        for (int d = 0; d < 8; d++) {
            float xA = bf2f(uA[d]), xB = bf2f(uB[d]);
            if (BNF) {
                xA = fmaxf(xA * sc[d] + sh[d], 0.0f);
                xB = fmaxf(xB * sc[d] + sh[d], 0.0f);
            }
            acc[d] += xA + xB;
        }
    }
    for (; e < e1; e += 2) {
        int s = csr[e];
        int4 v = *(const int4*)(X + (size_t)s * DD + j * 8);
        const ushort* u = (const ushort*)&v;
#pragma unroll
        for (int d = 0; d < 8; d++) {
            float x = bf2f(u[d]);
            if (BNF) x = fmaxf(x * sc[d] + sh[d], 0.0f);
            acc[d] += x;
        }
    }
#pragma unroll
    for (int d = 0; d < 8; d++)
        acc[d] += __shfl_down(acc[d], 32);
    if (h == 0) {
        float inv = invdeg[node];
        ushort ov[8];
#pragma unroll
        for (int d = 0; d < 8; d++) ov[d] = f2bf(acc[d] * inv);
        *(int4*)(AGG + (size_t)node * DD + j * 8) = *(int4*)ov;
    }
}

// ------- 80x128 GEMM, B-panel in registers -----------------------------------
// Per wave the whole B strip (32 cols x 256 K) is 16 fragments = 64 VGPRs.
// Preloaded per mat before the A staging barrier: L2 latency paid once, hidden
// under staging; the K loop touches only LDS (A) + registers (B).

template <int BNF>
__global__ __launch_bounds__(256, 3) void k_gemm8(
    const ushort* __restrict__ A1, const ushort* __restrict__ A2,
    const ushort* __restrict__ WtF1, const ushort* __restrict__ WtF2,
    const ushort* __restrict__ bias,
    const float* __restrict__ bnsc, const float* __restrict__ bnsh,
    ushort* __restrict__ H, float* __restrict__ psumT, float* __restrict__ psqT) {
    __shared__ ushort Als[BM][264];       // 80x264x2 = 42.2KB, stride 528B (2-way ok)
    __shared__ float colsum[128];
    __shared__ float colsq[128];
    const int m0 = blockIdx.x * BM;
    const int n0 = blockIdx.y * 128;
    const int tid = threadIdx.x;
    const int w = tid >> 6, lane = tid & 63;
    const int lr = lane & 15, q = lane >> 4;
    float4_t acc[5][2] = {};

    if (tid < 128) { colsum[tid] = 0.0f; colsq[tid] = 0.0f; }

    for (int mat = 0; mat < 2; ++mat) {
        const ushort* A = mat ? A2 : A1;
        const ushort* Wf = mat ? WtF2 : WtF1;
        // preload this wave's 16 B fragments (independent L2 loads, deep ILP)
        short8 bfr[8][2];
        const ushort* bb0 =
            Wf + (((size_t)(((n0 + w * 32) >> 4) * 8)) << 9) + lane * 8;
#pragma unroll
        for (int k8 = 0; k8 < 8; k8++)
#pragma unroll
            for (int in = 0; in < 2; in++)
                bfr[k8][in] = *(const short8*)(bb0 + (size_t)k8 * 512 + in * 4096);
        __syncthreads();                   // Als reads of prev mat done (also covers colsum init)
        // stage 80 rows x 256 cols: 2560 int4, 10 per thread, row-contiguous
#pragma unroll
        for (int i = 0; i < 10; i++) {
            int flat = tid + i * 256;      // 0..2559
            int r = flat >> 5;             // 0..79
            int c = (flat & 31) * 8;       // elem col 0..248
            int4 av = *(const int4*)(A + (size_t)(m0 + r) * DD + c);
            if (BNF && mat == 1) {
                ushort* u = (ushort*)&av;
#pragma unroll
                for (int d = 0; d < 8; d++)
                    u[d] = f2bf(fmaxf(bf2f(u[d]) * bnsc[c + d] + bnsh[c + d], 0.0f));
            }
            *(int4*)&Als[r][c] = av;
        }
        __syncthreads();
        // K loop: wave w covers cols n0 + w*32 .. +31, all 80 rows; B from regs
#pragma unroll
        for (int k0 = 0; k0 < 256; k0 += 32) {
            short8 af[5];
#pragma unroll
            for (int im = 0; im < 5; im++)
                af[im] = *(const short8*)&Als[im * 16 + lr][k0 + q * 8];
#pragma unroll
            for (int in = 0; in < 2; in++) {
#pragma unroll
                for (int im = 0; im < 5; im++)
                    acc[im][in] = __builtin_amdgcn_mfma_f32_16x16x32_bf16(
                        af[im], bfr[k0 >> 5][in], acc[im][in], 0, 0, 0);
            }
        }
    }

    // epilogue: C/D layout col=lane&15, row=(lane>>4)*4+reg
    const int mbase = m0 + q * 4;
#pragma unroll
    for (int in = 0; in < 2; ++in) {
        const int nl = w * 32 + in * 16 + lr;   // 0..127 local col
        const int n = n0 + nl;
        float b = bf2f(bias[n]);
        float s = 0.0f, s2 = 0.0f;
#pragma unroll
        for (int im = 0; im < 5; ++im) {
#pragma unroll
            for (int i = 0; i < 4; ++i) {
                int m = mbase + im * 16 + i;     // always < NN (exact tiling)
                float hv = acc[im][in][i] + b;
                ushort hb = f2bf(hv);
                H[(size_t)m * DD + n] = hb;
                float hq = bf2f(hb);
                s += hq;
                s2 += hq * hq;
            }
        }
        s += __shfl_xor(s, 16);  s += __shfl_xor(s, 32);
        s2 += __shfl_xor(s2, 16); s2 += __shfl_xor(s2, 32);
        if (q == 0) {
            atomicAdd(&colsum[nl], s);
            atomicAdd(&colsq[nl], s2);
        }
    }
    __syncthreads();
    if (tid < 128) {
        psumT[(size_t)(n0 + tid) * 256 + blockIdx.x] = colsum[tid];
        psqT[(size_t)(n0 + tid) * 256 + blockIdx.x] = colsq[tid];
    }
}

// ---------------- BN finalize (separate dispatch; kernel boundary = release) --
// Reads transposed psumT coalesced; partial order (b = t + 64k ascending) and
// shfl_down tree identical to the original -> bit-identical scale/shift.

__global__ __launch_bounds__(64) void k_bnfinal3(
    const float* __restrict__ psumT, const float* __restrict__ psqT,
    const ushort* __restrict__ gamma, const ushort* __restrict__ beta,
    float* __restrict__ scale, float* __restrict__ shift) {
    int c = blockIdx.x;     // 256
    int t = threadIdx.x;    // 64
    float s = 0.0f, s2 = 0.0f;
    for (int b = t; b < NBLK; b += 64) {
        s += psumT[(size_t)c * 256 + b];
        s2 += psqT[(size_t)c * 256 + b];
    }
#pragma unroll
    for (int o = 32; o; o >>= 1) {
        s += __shfl_down(s, o);
        s2 += __shfl_down(s2, o);
    }
    if (t == 0) {
        float mu = s * (1.0f / NN);
        float var = s2 * (1.0f / NN) - mu * mu;
        if (var < 0.0f) var = 0.0f;
        float rstd = rsqrtf(var + 1e-5f);
        float g = bf2f(gamma[c]);
        float b2 = bf2f(beta[c]);
        scale[c] = g * rstd;
        shift[c] = b2 - mu * g * rstd;
    }
}

// ---------------- fused pool (lazy BN) + MLP, weights in LDS ----------------
// Pool keeps per-dim ascending-i accumulation order (bit-identical); only the
// loads are batched 8-wide for latency hiding. MLP k-loops unchanged in order.

__global__ __launch_bounds__(256) void k_head(
    const ushort* __restrict__ Hb, const float* __restrict__ scale,
    const float* __restrict__ shift, const int* __restrict__ gstart,
    const ushort* __restrict__ fc1w, const ushort* __restrict__ fc1b,
    const ushort* __restrict__ fc2w, const ushort* __restrict__ fc2b,
    const ushort* __restrict__ fc3w, const ushort* __restrict__ fc3b,
    void* __restrict__ out, const int* __restrict__ fl) {
    __shared__ float g[256];
    __shared__ float h1[128];
    __shared__ float h2[64];
    __shared__ ushort w1[256 * 128];   // 64 KB
    __shared__ ushort w2[128 * 64];    // 16 KB
    __shared__ ushort w3[64 * 10];     // 1.25 KB
    int gid = blockIdx.x;
    int t = threadIdx.x;
    // stage MLP weights coalesced (int4 = 8 ushorts)
    for (int i = t; i < 256 * 128 / 8; i += 256) ((int4*)w1)[i] = ((const int4*)fc1w)[i];
    for (int i = t; i < 128 * 64 / 8; i += 256) ((int4*)w2)[i] = ((const int4*)fc2w)[i];
    if (t < 80) ((int4*)w3)[t] = ((const int4*)fc3w)[t];

    int s0 = gstart[gid], e = gstart[gid + 1];
    float sc = scale[t], sh = shift[t];
    float acc = 0.0f;
    int i = s0;
    for (; i + 7 < e; i += 8) {        // 8 loads in flight, adds stay in order
        float v[8];
#pragma unroll
        for (int r = 0; r < 8; r++) v[r] = bf2f(Hb[(size_t)(i + r) * DD + t]);
#pragma unroll
        for (int r = 0; r < 8; r++) acc += fmaxf(v[r] * sc + sh, 0.0f);
    }
    for (; i < e; i++)
        acc += fmaxf(bf2f(Hb[(size_t)i * DD + t]) * sc + sh, 0.0f);
    g[t] = acc / fmaxf((float)(e - s0), 1.0f);
    __syncthreads();
    if (t < 128) {
        float a = bf2f(fc1b[t]);
#pragma unroll 8
        for (int k = 0; k < 256; k++)
            a += g[k] * bf2f(w1[k * 128 + t]);
        h1[t] = fmaxf(a, 0.0f);
    }
    __syncthreads();
    if (t < 64) {
        float a2 = bf2f(fc2b[t]);
#pragma unroll 8
        for (int k = 0; k < 128; k++)
            a2 += h1[k] * bf2f(w2[k * 64 + t]);
        h2[t] = fmaxf(a2, 0.0f);
    }
    __syncthreads();
    if (t < 10) {
        float a3 = bf2f(fc3b[t]);
#pragma unroll 8
        for (int k = 0; k < 64; k++)
            a3 += h2[k] * bf2f(w3[k * 10 + t]);
        if (fl[2]) ((__hip_bfloat16*)out)[gid * 10 + t] = __float2bfloat16(a3);
        else       ((float*)out)[gid * 10 + t] = a3;
    }
}

// ---------------- host ----------------

static inline char* bump(char*& p, size_t n) {
    char* r = p;
    p += (n + 255) & ~(size_t)255;
    return r;
}

extern "C" void kernel_launch(void* const* d_in, const int* in_sizes, int n_in,
                              void* d_out, int out_size, void* d_ws, size_t ws_size,
                              hipStream_t stream) {
    const void* x_in  = d_in[0];
    const int*  ei    = (const int*)d_in[1];
    const int*  batch = (const int*)d_in[2];
    const void* Wl    = d_in[3];
    const void* bl    = d_in[4];
    const void* Wr    = d_in[5];
    const void* gamma = d_in[6];
    const void* beta  = d_in[7];

    char* p = (char*)d_ws;
    int*    flags    = (int*)bump(p, 256);
    ushort* wtL      = (ushort*)bump(p, (size_t)NL * 65536 * 2);   // fragment layout
    ushort* wtR      = (ushort*)bump(p, (size_t)NL * 65536 * 2);   // fragment layout
    ushort* xcan     = (ushort*)bump(p, (size_t)NN * DD * 2);
    ushort* pcan     = (ushort*)bump(p, (size_t)PTOT * 2);
    int*    deg      = (int*)bump(p, NN * 4);
    int*    rowst    = (int*)bump(p, (NN + 1) * 4);
    int*    cursor   = (int*)bump(p, NN * 4);
    float*  invdeg   = (float*)bump(p, NN * 4);
    int*    csr      = (int*)bump(p, NE * 4);
    int*    gstart   = (int*)bump(p, (NG + 1) * 4);
    ushort* agg      = (ushort*)bump(p, (size_t)NN * DD * 2);
    ushort* hb0      = (ushort*)bump(p, (size_t)NN * DD * 2);
    ushort* hb1      = (ushort*)bump(p, (size_t)NN * DD * 2);
    float*  psumT    = (float*)bump(p, (size_t)DD * 256 * 4);
    float*  psqT     = (float*)bump(p, (size_t)DD * 256 * 4);
    float*  scale    = (float*)bump(p, DD * 4);
    float*  shift    = (float*)bump(p, DD * 4);

    if ((size_t)(p - (char*)d_ws) > ws_size) return;

    ushort* blc = pcan + POFF_BL;
    ushort* gac = pcan + POFF_GA;
    ushort* bec = pcan + POFF_BE;
    ushort* f1w = pcan + POFF_F1W;
    ushort* f1b = pcan + POFF_F1B;
    ushort* f2w = pcan + POFF_F2W;
    ushort* f2b = pcan + POFF_F2B;
    ushort* f3w = pcan + POFF_F3W;
    ushort* f3b = pcan + POFF_F3B;

    // ---- host-side dtype resolution from in_sizes (byte counts). If anything
    // is ambiguous, fall back to the device-detection path (bit-identical).
    const long long xb_sz = (long long)NN * DD * 2, xf_sz = (long long)NN * DD * 4;
    const long long e8_sz = (long long)2 * NE * 8, e4_sz = (long long)2 * NE * 4;
    const long long b8_sz = (long long)NN * 8, b4_sz = (long long)NN * 4;
    const long long w_sz_b = (long long)NL * DD * DD * 2, w_sz_f = (long long)NL * DD * DD * 4;
    int xb = in_sizes[0] == xb_sz, xf = in_sizes[0] == xf_sz;
    int e8 = in_sizes[1] == e8_sz, e4 = in_sizes[1] == e4_sz;
    int b8 = in_sizes[2] == b8_sz, b4 = in_sizes[2] == b4_sz;
    int wb = in_sizes[3] == w_sz_b, wf = in_sizes[3] == w_sz_f;
    int known = (xb ^ xf) && (e8 ^ e4) && (b8 ^ b4) && (wb ^ wf) &&
                ((xb && wb) || (xf && wf));

    if (known) {
        k_init2<<<80, 256, 0, stream>>>(flags, deg, e8, b8, xb);
        int blkoff = xb ? NB_CVT8 : 0;    // bf16 input: skip canonicalization copy
        k_prep<<<NB_PREP - blkoff, 256, 0, stream>>>(
            x_in, Wl, Wr, ei, batch,
            bl, gamma, beta, d_in[8], d_in[9], d_in[10], d_in[11], d_in[12], d_in[13],
            xcan, wtL, wtR, pcan, deg, gstart, flags, blkoff);
    } else {
        k_init<<<80, 256, 0, stream>>>(ei, batch, (const ushort*)x_in, flags, deg);
        k_prep<<<NB_PREP, 256, 0, stream>>>(
            x_in, Wl, Wr, ei, batch,
            bl, gamma, beta, d_in[8], d_in[9], d_in[10], d_in[11], d_in[12], d_in[13],
            xcan, wtL, wtR, pcan, deg, gstart, flags, 0);
    }
    k_scan<<<NBKT, 256, 0, stream>>>(deg, rowst, cursor, invdeg);
    k_fill<<<(NE + 255) / 256, 256, 0, stream>>>(ei, cursor, csr, flags);

    // layer-0 X source: raw input when it is already bf16 (copy was bitwise)
    const ushort* x0 = (known && xb) ? (const ushort*)x_in : xcan;

    ushort* hbuf[2] = {hb0, hb1};
    const ushort* xsrc = x0;
    for (int l = 0; l < NL; l++) {
        ushort* hdst = hbuf[l & 1];
        const ushort* wl = wtL + (size_t)l * 65536;
        const ushort* wr = wtR + (size_t)l * 65536;
        if (l == 0) {
            k_agg4<0><<<(NN + 3) / 4, 256, 0, stream>>>(xsrc, rowst, csr, invdeg,
                                                        scale, shift, agg);
            k_gemm8<0><<<dim3(NBLK, 2), 256, 0, stream>>>(
                agg, xsrc, wl, wr, blc, scale, shift, hdst, psumT, psqT);
        } else {
            k_agg4<1><<<(NN + 3) / 4, 256, 0, stream>>>(xsrc, rowst, csr, invdeg,
                                                        scale, shift, agg);
            k_gemm8<1><<<dim3(NBLK, 2), 256, 0, stream>>>(
                agg, xsrc, wl, wr, blc + l * DD, scale, shift, hdst, psumT, psqT);
        }
        k_bnfinal3<<<DD, 64, 0, stream>>>(psumT, psqT, gac + l * DD, bec + l * DD,
                                          scale, shift);
        xsrc = hdst;
    }

    k_head<<<NG, 256, 0, stream>>>(xsrc, scale, shift, gstart,
                                   f1w, f1b, f2w, f2b, f3w, f3b, d_out, flags);
}